// Round 2
// baseline (235.013 us; speedup 1.0000x reference)
//
#include <hip/hip_runtime.h>
#include <hip/hip_bf16.h>

#define NGRAPH 256
#define NN     128   // nodes per graph
#define NT     16    // templates
#define NM     10    // template nodes
#define OUTER_IT 5
#define SINK_IT  20
// K = exp(-2*tens/EPS) = exp(-20*tens)
#define COST_SCALE 20.0f

// ---- 64-lane all-reduce sum via DPP (VALU pipe, no LDS) ----
template <int CTRL>
__device__ __forceinline__ float dpp_add(float a) {
  int t = __builtin_amdgcn_update_dpp(0, __float_as_int(a), CTRL, 0xf, 0xf, true);
  return a + __int_as_float(t);
}

__device__ __forceinline__ float wave_allsum(float x) {
  float a = x;
  a = dpp_add<0x111>(a);  // row_shr:1
  a = dpp_add<0x112>(a);  // row_shr:2
  a = dpp_add<0x114>(a);  // row_shr:4
  a = dpp_add<0x118>(a);  // row_shr:8  -> lane 15 of each row16 has row sum
  a = dpp_add<0x142>(a);  // row_bcast:15
  a = dpp_add<0x143>(a);  // row_bcast:31 -> lane 63 has full sum
  return __int_as_float(__builtin_amdgcn_readlane(__float_as_int(a), 63));
}

// One wave (64 threads) per (graph b, template t) pair. Lane owns rows
// lane and lane+64 of P/K. Adjacency kept as LDS bitmask; P round-trips
// through LDS between outer iterations for the C1@P gather.
__global__ __launch_bounds__(64, 4)
void tgw_kernel(const int* __restrict__ ei,
                const float* __restrict__ tadj,
                const float* __restrict__ q0g,
                float* __restrict__ out,
                int E, int ne) {
  const int b    = blockIdx.x >> 4;
  const int t    = blockIdx.x & 15;
  const int lane = threadIdx.x;

  __shared__ unsigned adj[NN][4];                 // 128x128 bitmask, 2 KB
  __shared__ __align__(16) float Pls[NN][12];     // P rows, stride 12 floats (48B, 16B-aligned)
  __shared__ float C2s[NM][NM];
  __shared__ float q0s[NM];

  // zero bitmask
  unsigned* aflat = &adj[0][0];
  #pragma unroll
  for (int i = 0; i < 8; ++i) aflat[lane + 64 * i] = 0u;

  // stage template adjacency + q0 row (fp32)
  for (int i = lane; i < NM * NM; i += 64)
    (&C2s[0][0])[i] = tadj[t * NM * NM + i];
  if (lane < NM) q0s[lane] = q0g[t * NM + lane];
  __syncthreads();

  // build symmetric 0/1 adjacency from edge list (duplicates/self-loops fine)
  const int* srcp = ei;
  const int* dstp = ei + E;
  const int ebase = b * ne;
  for (int e = lane; e < ne; e += 64) {
    int s = srcp[ebase + e] & (NN - 1);   // local id: global - g*128
    int d = dstp[ebase + e] & (NN - 1);
    atomicOr(&adj[s][d >> 5], 1u << (d & 31));
    atomicOr(&adj[d][s >> 5], 1u << (s & 31));
  }
  __syncthreads();

  // q = softmax(q0 row), f2q[j] = sum_m C2[j][m]^2 q[m]   (redundant per lane, trivial)
  float qv[NM], f2q[NM];
  {
    float mx = q0s[0];
    #pragma unroll
    for (int j = 1; j < NM; ++j) mx = fmaxf(mx, q0s[j]);
    float s = 0.f;
    #pragma unroll
    for (int j = 0; j < NM; ++j) { qv[j] = __expf(q0s[j] - mx); s += qv[j]; }
    float inv = __builtin_amdgcn_rcpf(s);
    #pragma unroll
    for (int j = 0; j < NM; ++j) qv[j] *= inv;
  }
  #pragma unroll
  for (int j = 0; j < NM; ++j) {
    float a = 0.f;
    #pragma unroll
    for (int m = 0; m < NM; ++m) { float c = C2s[j][m]; a = fmaf(c * c, qv[m], a); }
    f2q[j] = a;
  }

  // own adjacency rows as 2x u64 each; f1p = deg/128 (C1*C1 == C1)
  unsigned long long mk0[2], mk1[2];
  mk0[0] = adj[lane][0]      | ((unsigned long long)adj[lane][1]      << 32);
  mk0[1] = adj[lane][2]      | ((unsigned long long)adj[lane][3]      << 32);
  mk1[0] = adj[lane + 64][0] | ((unsigned long long)adj[lane + 64][1] << 32);
  mk1[1] = adj[lane + 64][2] | ((unsigned long long)adj[lane + 64][3] << 32);
  const float pw = 1.0f / 128.0f;
  float f1p0 = (float)(__popcll(mk0[0]) + __popcll(mk0[1])) * pw;
  float f1p1 = (float)(__popcll(mk1[0]) + __popcll(mk1[1])) * pw;

  // P0 = p q^T
  #pragma unroll
  for (int j = 0; j < NM; ++j) {
    float pv = qv[j] * pw;
    Pls[lane][j]      = pv;
    Pls[lane + 64][j] = pv;
  }
  __syncthreads();

  // S[m] = sum_{k in adj(row)} P[k][m]  (sparse gather over bitmask)
  auto gather = [&](const unsigned long long* mk, float* S) {
    #pragma unroll
    for (int j = 0; j < NM; ++j) S[j] = 0.f;
    #pragma unroll
    for (int w = 0; w < 2; ++w) {
      unsigned long long bits = mk[w];
      while (bits) {
        int k = (w << 6) + (int)__builtin_ctzll(bits);
        bits &= bits - 1;
        const float* row = Pls[k];
        #pragma unroll
        for (int j = 0; j < NM; ++j) S[j] += row[j];
      }
    }
  };

  float K0[NM], K1[NM], vv[NM];
  float u0 = 0.f, u1 = 0.f;

  for (int o = 0; o < OUTER_IT; ++o) {
    float S0[NM], S1[NM];
    gather(mk0, S0);
    gather(mk1, S1);
    // K = exp(-20 * (f1p_i + f2q_j - 2 * (S C2^T)_ij))
    #pragma unroll
    for (int j = 0; j < NM; ++j) {
      float cr0 = 0.f, cr1 = 0.f;
      #pragma unroll
      for (int m = 0; m < NM; ++m) {
        float c = C2s[j][m];
        cr0 = fmaf(S0[m], c, cr0);
        cr1 = fmaf(S1[m], c, cr1);
      }
      float t0 = f1p0 + f2q[j] - 2.f * cr0;
      float t1 = f1p1 + f2q[j] - 2.f * cr1;
      K0[j] = __expf(-COST_SCALE * t0);
      K1[j] = __expf(-COST_SCALE * t1);
    }
    // Sinkhorn: u = p/(K v), v = q/(K^T u); v starts at ones
    #pragma unroll
    for (int j = 0; j < NM; ++j) vv[j] = 1.f;
    for (int it = 0; it < SINK_IT; ++it) {
      float d0 = 0.f, d1 = 0.f;
      #pragma unroll
      for (int j = 0; j < NM; ++j) { d0 = fmaf(K0[j], vv[j], d0); d1 = fmaf(K1[j], vv[j], d1); }
      u0 = pw * __builtin_amdgcn_rcpf(d0);
      u1 = pw * __builtin_amdgcn_rcpf(d1);
      #pragma unroll
      for (int j = 0; j < NM; ++j) {
        float w  = fmaf(K0[j], u0, K1[j] * u1);   // partial K^T u over this lane's 2 rows
        float cs = wave_allsum(w);                 // full column sum, broadcast
        vv[j] = qv[j] * __builtin_amdgcn_rcpf(cs);
      }
    }
    // P = diag(u) K diag(v) -> LDS for next gather
    #pragma unroll
    for (int j = 0; j < NM; ++j) {
      Pls[lane][j]      = u0 * K0[j] * vv[j];
      Pls[lane + 64][j] = u1 * K1[j] * vv[j];
    }
    __syncthreads();
  }

  // GW[b,t] = sum_ij tens(P)_ij * P_ij with final P
  float S0[NM], S1[NM];
  gather(mk0, S0);
  gather(mk1, S1);
  float acc = 0.f;
  #pragma unroll
  for (int j = 0; j < NM; ++j) {
    float cr0 = 0.f, cr1 = 0.f;
    #pragma unroll
    for (int m = 0; m < NM; ++m) {
      float c = C2s[j][m];
      cr0 = fmaf(S0[m], c, cr0);
      cr1 = fmaf(S1[m], c, cr1);
    }
    float t0 = f1p0 + f2q[j] - 2.f * cr0;
    float t1 = f1p1 + f2q[j] - 2.f * cr1;
    acc += t0 * (u0 * K0[j] * vv[j]) + t1 * (u1 * K1[j] * vv[j]);
  }
  float total = wave_allsum(acc);
  if (lane == 0) out[b * NT + t] = total;
}

extern "C" void kernel_launch(void* const* d_in, const int* in_sizes, int n_in,
                              void* d_out, int out_size, void* d_ws, size_t ws_size,
                              hipStream_t stream) {
  // inputs: 0 x(f32, unused) 1 edge_index(int32) 2 batch(int32, unused)
  //         3 tplt_adjacencies(f32) 4 tplt_features(f32, unused) 5 q0(f32)
  const int* ei    = (const int*)d_in[1];
  const float* c2  = (const float*)d_in[3];
  const float* q0  = (const float*)d_in[5];
  float* out       = (float*)d_out;
  const int E  = in_sizes[1] / 2;      // total edges
  const int ne = E / NGRAPH;           // edges per graph (1024)
  tgw_kernel<<<dim3(NGRAPH * NT), dim3(64), 0, stream>>>(ei, c2, q0, out, E, ne);
}

// Round 3
// 226.914 us; speedup vs baseline: 1.0357x; 1.0357x over previous
//
#include <hip/hip_runtime.h>

#define NGRAPH 256
#define NN     128   // nodes per graph
#define NT     16    // templates
#define NM     10    // template nodes
#define OUTER_IT 5
#define SINK_IT  20
// K = exp(-2*tens/EPS) = exp(-20*tens)
#define COST_SCALE 20.0f

typedef unsigned long long u64;

// DPP xor-butterfly add within each 16-lane row; after all 4 steps every
// lane of the row holds the 16-lane sum. Masks {1,2,7,15} span (Z2)^4.
template <int CTRL>
__device__ __forceinline__ float dpp_add(float a) {
  int t = __builtin_amdgcn_update_dpp(0, __float_as_int(a), CTRL, 0xf, 0xf, true);
  return a + __int_as_float(t);
}
__device__ __forceinline__ float allsum16(float x) {
  x = dpp_add<0xB1>(x);    // quad_perm [1,0,3,2] : xor 1
  x = dpp_add<0x4E>(x);    // quad_perm [2,3,0,1] : xor 2
  x = dpp_add<0x141>(x);   // row_half_mirror     : xor 7
  x = dpp_add<0x140>(x);   // row_mirror          : xor 15
  return x;
}

// One 16-lane group per (graph b, template t) pair; 4 pairs (templates
// tb..tb+3 of one graph) per 64-thread block. Lane owns 8 rows
// r = sub + 16*jj of K/P. Adjacency: shared LDS bitmask. P: LDS, fp32,
// row stride 12 floats (b128-aligned).
__global__ __launch_bounds__(64, 1)
void tgw_kernel(const int* __restrict__ ei,
                const float* __restrict__ tadj,
                const float* __restrict__ q0g,
                float* __restrict__ out,
                int E, int ne) {
  const int lane = threadIdx.x;
  const int g    = lane >> 4;        // template slot 0..3
  const int sub  = lane & 15;
  const int b    = blockIdx.x >> 2;
  const int tb   = (blockIdx.x & 3) * 4;

  __shared__ unsigned adj[NN][4];                    // 2 KB shared by 4 pairs
  __shared__ __align__(16) float Pls[4][129][12];    // ~24.8 KB
  __shared__ __align__(16) float C2s[4][NM][12];     // rows padded to 48B
  __shared__ float q0s[4][NM];

  // ---- stage ----
  for (int i = lane; i < NN * 4; i += 64) (&adj[0][0])[i] = 0u;
  for (int i = lane; i < 4 * NM * NM; i += 64) {
    int tt = i / (NM * NM), rem = i % (NM * NM);
    C2s[tt][rem / NM][rem % NM] = tadj[(tb + tt) * NM * NM + rem];
  }
  for (int i = lane; i < 4 * NM; i += 64)
    q0s[i / NM][i % NM] = q0g[tb * NM + i];
  __syncthreads();

  // symmetric 0/1 adjacency from edge list
  const int* srcp = ei;
  const int* dstp = ei + E;
  const int ebase = b * ne;
  for (int e = lane; e < ne; e += 64) {
    int s = srcp[ebase + e] & (NN - 1);
    int d = dstp[ebase + e] & (NN - 1);
    atomicOr(&adj[s][d >> 5], 1u << (d & 31));
    atomicOr(&adj[d][s >> 5], 1u << (s & 31));
  }
  __syncthreads();

  // ---- per-pair scalars ----
  float qv[NM], f2q[NM];
  {
    float mx = q0s[g][0];
    #pragma unroll
    for (int j = 1; j < NM; ++j) mx = fmaxf(mx, q0s[g][j]);
    float s = 0.f;
    #pragma unroll
    for (int j = 0; j < NM; ++j) { qv[j] = __expf(q0s[g][j] - mx); s += qv[j]; }
    float inv = __builtin_amdgcn_rcpf(s);
    #pragma unroll
    for (int j = 0; j < NM; ++j) qv[j] *= inv;
  }
  #pragma unroll
  for (int j = 0; j < NM; ++j) {
    float a = 0.f;
    #pragma unroll
    for (int m = 0; m < NM; ++m) { float c = C2s[g][j][m]; a = fmaf(c * c, qv[m], a); }
    f2q[j] = a;
  }

  const float pw = 1.0f / 128.0f;
  float f1p[8];
  #pragma unroll
  for (int jj = 0; jj < 8; ++jj) {
    uint4 mm = *(const uint4*)&adj[sub + 16 * jj][0];
    u64 m0 = mm.x | ((u64)mm.y << 32), m1 = mm.z | ((u64)mm.w << 32);
    f1p[jj] = (float)(__popcll(m0) + __popcll(m1)) * pw;   // C1*C1 == C1
  }

  // sparse gather of 4 rows of S = C1 @ P from LDS P
  auto gather4 = [&](int jj0, float S4[4][NM]) {
    #pragma unroll
    for (int c = 0; c < 4; ++c) {
      const int r = sub + 16 * (jj0 + c);
      uint4 mm = *(const uint4*)&adj[r][0];
      u64 m0 = mm.x | ((u64)mm.y << 32), m1 = mm.z | ((u64)mm.w << 32);
      float S[NM];
      #pragma unroll
      for (int j = 0; j < NM; ++j) S[j] = 0.f;
      while (m0) {
        int k = (int)__builtin_ctzll(m0); m0 &= m0 - 1;
        const float* row = &Pls[g][k][0];
        float4 a = *(const float4*)row;
        float4 bb = *(const float4*)(row + 4);
        float2 cc = *(const float2*)(row + 8);
        S[0] += a.x;  S[1] += a.y;  S[2] += a.z;  S[3] += a.w;
        S[4] += bb.x; S[5] += bb.y; S[6] += bb.z; S[7] += bb.w;
        S[8] += cc.x; S[9] += cc.y;
      }
      while (m1) {
        int k = 64 + (int)__builtin_ctzll(m1); m1 &= m1 - 1;
        const float* row = &Pls[g][k][0];
        float4 a = *(const float4*)row;
        float4 bb = *(const float4*)(row + 4);
        float2 cc = *(const float2*)(row + 8);
        S[0] += a.x;  S[1] += a.y;  S[2] += a.z;  S[3] += a.w;
        S[4] += bb.x; S[5] += bb.y; S[6] += bb.z; S[7] += bb.w;
        S[8] += cc.x; S[9] += cc.y;
      }
      #pragma unroll
      for (int j = 0; j < NM; ++j) S4[c][j] = S[j];
    }
  };

  float Kc[8][NM], vv[NM], uu[8];

  for (int o = 0; o < OUTER_IT; ++o) {
    // ---- cost -> K = exp(-20 * (f1p_i + f2q_j - 2 (S C2^T)_ij)) ----
    #pragma unroll
    for (int half = 0; half < 2; ++half) {
      const int jj0 = half * 4;
      float S4[4][NM];
      if (o == 0) {
        // P0 = p q^T  =>  S[i][m] = (deg_i/128) * q[m] = f1p_i * q[m]
        #pragma unroll
        for (int c = 0; c < 4; ++c)
          #pragma unroll
          for (int j = 0; j < NM; ++j) S4[c][j] = f1p[jj0 + c] * qv[j];
      } else {
        gather4(jj0, S4);
      }
      #pragma unroll
      for (int j = 0; j < NM; ++j) {
        const float* c2r = &C2s[g][j][0];
        float4 ca = *(const float4*)c2r;
        float4 cb = *(const float4*)(c2r + 4);
        float2 cd = *(const float2*)(c2r + 8);
        #pragma unroll
        for (int c = 0; c < 4; ++c) {
          float cr = S4[c][0] * ca.x;
          cr = fmaf(S4[c][1], ca.y, cr); cr = fmaf(S4[c][2], ca.z, cr);
          cr = fmaf(S4[c][3], ca.w, cr); cr = fmaf(S4[c][4], cb.x, cr);
          cr = fmaf(S4[c][5], cb.y, cr); cr = fmaf(S4[c][6], cb.z, cr);
          cr = fmaf(S4[c][7], cb.w, cr); cr = fmaf(S4[c][8], cd.x, cr);
          cr = fmaf(S4[c][9], cd.y, cr);
          float tv = f1p[jj0 + c] + f2q[j] - 2.f * cr;
          Kc[jj0 + c][j] = __expf(-COST_SCALE * tv);
        }
      }
    }

    // ---- Sinkhorn (v starts at ones) ----
    #pragma unroll
    for (int j = 0; j < NM; ++j) vv[j] = 1.f;
    for (int it = 0; it < SINK_IT; ++it) {
      #pragma unroll
      for (int jj = 0; jj < 8; ++jj) {
        float d = Kc[jj][0] * vv[0];
        #pragma unroll
        for (int j = 1; j < NM; ++j) d = fmaf(Kc[jj][j], vv[j], d);
        uu[jj] = pw * __builtin_amdgcn_rcpf(d);
      }
      #pragma unroll
      for (int j = 0; j < NM; ++j) {
        float w = Kc[0][j] * uu[0];
        #pragma unroll
        for (int jj = 1; jj < 8; ++jj) w = fmaf(Kc[jj][j], uu[jj], w);
        float cs = allsum16(w);
        vv[j] = qv[j] * __builtin_amdgcn_rcpf(cs);
      }
    }

    // ---- P = diag(u) K diag(v) -> LDS ----
    __syncthreads();   // all gathers of old P done before overwrite
    #pragma unroll
    for (int jj = 0; jj < 8; ++jj) {
      const int r = sub + 16 * jj;
      float x[NM];
      #pragma unroll
      for (int j = 0; j < NM; ++j) x[j] = uu[jj] * Kc[jj][j] * vv[j];
      float* row = &Pls[g][r][0];
      *(float4*)row       = make_float4(x[0], x[1], x[2], x[3]);
      *(float4*)(row + 4) = make_float4(x[4], x[5], x[6], x[7]);
      *(float2*)(row + 8) = make_float2(x[8], x[9]);
    }
    __syncthreads();
  }

  // ---- GW = sum_ij tens(P)_ij * P_ij ----
  float acc = 0.f;
  #pragma unroll
  for (int half = 0; half < 2; ++half) {
    const int jj0 = half * 4;
    float S4[4][NM];
    gather4(jj0, S4);
    #pragma unroll
    for (int j = 0; j < NM; ++j) {
      const float* c2r = &C2s[g][j][0];
      float4 ca = *(const float4*)c2r;
      float4 cb = *(const float4*)(c2r + 4);
      float2 cd = *(const float2*)(c2r + 8);
      #pragma unroll
      for (int c = 0; c < 4; ++c) {
        const int jj = jj0 + c;
        float cr = S4[c][0] * ca.x;
        cr = fmaf(S4[c][1], ca.y, cr); cr = fmaf(S4[c][2], ca.z, cr);
        cr = fmaf(S4[c][3], ca.w, cr); cr = fmaf(S4[c][4], cb.x, cr);
        cr = fmaf(S4[c][5], cb.y, cr); cr = fmaf(S4[c][6], cb.z, cr);
        cr = fmaf(S4[c][7], cb.w, cr); cr = fmaf(S4[c][8], cd.x, cr);
        cr = fmaf(S4[c][9], cd.y, cr);
        float tv = f1p[jj] + f2q[j] - 2.f * cr;
        float Pv = uu[jj] * Kc[jj][j] * vv[j];
        acc = fmaf(tv, Pv, acc);
      }
    }
  }
  float total = allsum16(acc);
  if (sub == 0) out[b * NT + tb + g] = total;
}

extern "C" void kernel_launch(void* const* d_in, const int* in_sizes, int n_in,
                              void* d_out, int out_size, void* d_ws, size_t ws_size,
                              hipStream_t stream) {
  // inputs: 0 x(f32, unused) 1 edge_index(int32) 2 batch(int32, unused)
  //         3 tplt_adjacencies(f32) 4 tplt_features(f32, unused) 5 q0(f32)
  const int* ei   = (const int*)d_in[1];
  const float* c2 = (const float*)d_in[3];
  const float* q0 = (const float*)d_in[5];
  float* out      = (float*)d_out;
  const int E  = in_sizes[1] / 2;
  const int ne = E / NGRAPH;
  tgw_kernel<<<dim3(NGRAPH * 4), dim3(64), 0, stream>>>(ei, c2, q0, out, E, ne);
}

// Round 4
// 203.760 us; speedup vs baseline: 1.1534x; 1.1136x over previous
//
#include <hip/hip_runtime.h>

#define NGRAPH 256
#define NN     128   // nodes per graph
#define NT     16    // templates
#define NM     10    // template nodes
#define OUTER_IT 5
#define SINK_IT  20
// K = exp(-2*tens/EPS) = exp(-20*tens)
#define COST_SCALE 20.0f

typedef unsigned long long u64;

// DPP xor-butterfly add within a 16-lane row (masks {1,2,7,15} span (Z2)^4).
template <int CTRL>
__device__ __forceinline__ float dpp_add(float a) {
  int t = __builtin_amdgcn_update_dpp(0, __float_as_int(a), CTRL, 0xf, 0xf, true);
  return a + __int_as_float(t);
}
// Sum over each 32-lane group; result broadcast to all lanes of the group.
__device__ __forceinline__ float allsum32(float x) {
  x = dpp_add<0xB1>(x);    // quad_perm xor 1
  x = dpp_add<0x4E>(x);    // quad_perm xor 2
  x = dpp_add<0x141>(x);   // row_half_mirror: xor 7
  x = dpp_add<0x140>(x);   // row_mirror: xor 15
  int sw = __builtin_amdgcn_ds_swizzle(__float_as_int(x), 0x401F); // xor 16
  return x + __int_as_float(sw);
}

// 32 lanes per (graph b, template t) pair, 2 pairs (consecutive templates of
// one graph) per 64-thread single-wave block. Lane owns 4 rows r = sub + 32*c.
// Adjacency: LDS bitmask (shared). P: LDS fp32, row stride 12 floats.
__global__ __launch_bounds__(64, 2)
void tgw_kernel(const int* __restrict__ ei,
                const float* __restrict__ tadj,
                const float* __restrict__ q0g,
                float* __restrict__ out,
                int E, int ne) {
  const int lane = threadIdx.x;
  const int p    = lane >> 5;        // pair slot 0/1
  const int sub  = lane & 31;
  const int b    = blockIdx.x >> 3;
  const int t0   = (blockIdx.x & 7) * 2;   // templates t0, t0+1

  __shared__ __align__(16) unsigned adj[NN][4];    // 2 KB
  __shared__ __align__(16) float Pls[2][NN][12];   // 12 KB
  __shared__ __align__(16) float C2s[2][NM][12];   // rows padded to 48 B
  __shared__ float q0s[2][NM];

  // ---- stage ----
  for (int i = lane; i < NN * 4; i += 64) (&adj[0][0])[i] = 0u;
  for (int i = lane; i < 2 * NM * NM; i += 64) {
    int tt = i / (NM * NM), rem = i % (NM * NM);
    C2s[tt][rem / NM][rem % NM] = tadj[(t0 + tt) * NM * NM + rem];
  }
  if (lane < 2 * NM) q0s[lane / NM][lane % NM] = q0g[t0 * NM + lane];
  __syncthreads();

  // symmetric 0/1 adjacency from the edge list (dups/self-loops harmless)
  const int* srcp = ei;
  const int* dstp = ei + E;
  const int ebase = b * ne;
  for (int e = lane; e < ne; e += 64) {
    int s = srcp[ebase + e] & (NN - 1);
    int d = dstp[ebase + e] & (NN - 1);
    atomicOr(&adj[s][d >> 5], 1u << (d & 31));
    atomicOr(&adj[d][s >> 5], 1u << (s & 31));
  }
  __syncthreads();

  // ---- per-pair scalars ----
  float qv[NM], f2q[NM];
  {
    float mx = q0s[p][0];
    #pragma unroll
    for (int j = 1; j < NM; ++j) mx = fmaxf(mx, q0s[p][j]);
    float s = 0.f;
    #pragma unroll
    for (int j = 0; j < NM; ++j) { qv[j] = __expf(q0s[p][j] - mx); s += qv[j]; }
    float inv = __builtin_amdgcn_rcpf(s);
    #pragma unroll
    for (int j = 0; j < NM; ++j) qv[j] *= inv;
  }
  #pragma unroll
  for (int j = 0; j < NM; ++j) {
    float a = 0.f;
    #pragma unroll
    for (int m = 0; m < NM; ++m) { float c = C2s[p][j][m]; a = fmaf(c * c, qv[m], a); }
    f2q[j] = a;
  }

  const float pw = 1.0f / 128.0f;
  float f1p[4];
  #pragma unroll
  for (int c = 0; c < 4; ++c) {
    uint4 mm = *(const uint4*)&adj[sub + 32 * c][0];
    u64 m0 = mm.x | ((u64)mm.y << 32), m1 = mm.z | ((u64)mm.w << 32);
    f1p[c] = (float)(__popcll(m0) + __popcll(m1)) * pw;   // C1*C1 == C1
  }

  // sparse gather S = (C1 @ P)[row r] from LDS P
  const float* Pbase = &Pls[p][0][0];
  auto gatherRow = [&](int r, float* S) {
    uint4 mm = *(const uint4*)&adj[r][0];
    u64 m0 = mm.x | ((u64)mm.y << 32), m1 = mm.z | ((u64)mm.w << 32);
    #pragma unroll
    for (int j = 0; j < NM; ++j) S[j] = 0.f;
    while (m0) {
      int k = (int)__builtin_ctzll(m0); m0 &= m0 - 1;
      const float* row = Pbase + k * 12;
      float4 a = *(const float4*)row;
      float4 bb = *(const float4*)(row + 4);
      float2 cc = *(const float2*)(row + 8);
      S[0] += a.x;  S[1] += a.y;  S[2] += a.z;  S[3] += a.w;
      S[4] += bb.x; S[5] += bb.y; S[6] += bb.z; S[7] += bb.w;
      S[8] += cc.x; S[9] += cc.y;
    }
    while (m1) {
      int k = 64 + (int)__builtin_ctzll(m1); m1 &= m1 - 1;
      const float* row = Pbase + k * 12;
      float4 a = *(const float4*)row;
      float4 bb = *(const float4*)(row + 4);
      float2 cc = *(const float2*)(row + 8);
      S[0] += a.x;  S[1] += a.y;  S[2] += a.z;  S[3] += a.w;
      S[4] += bb.x; S[5] += bb.y; S[6] += bb.z; S[7] += bb.w;
      S[8] += cc.x; S[9] += cc.y;
    }
  };

  float Kc[4][NM], vv[NM], uu[4];

  for (int o = 0; o < OUTER_IT; ++o) {
    // ---- cost -> K = exp(-20 * (f1p_i + f2q_j - 2 (S C2^T)_ij)) ----
    float S4[4][NM];
    if (o == 0) {
      // P0 = p q^T  =>  S[i][m] = f1p_i * q[m]
      #pragma unroll
      for (int c = 0; c < 4; ++c)
        #pragma unroll
        for (int j = 0; j < NM; ++j) S4[c][j] = f1p[c] * qv[j];
    } else {
      #pragma unroll
      for (int c = 0; c < 4; ++c) gatherRow(sub + 32 * c, S4[c]);
    }
    #pragma unroll
    for (int j = 0; j < NM; ++j) {
      const float* c2r = &C2s[p][j][0];
      float4 ca = *(const float4*)c2r;
      float4 cb = *(const float4*)(c2r + 4);
      float2 cd = *(const float2*)(c2r + 8);
      #pragma unroll
      for (int c = 0; c < 4; ++c) {
        float cr = S4[c][0] * ca.x;
        cr = fmaf(S4[c][1], ca.y, cr); cr = fmaf(S4[c][2], ca.z, cr);
        cr = fmaf(S4[c][3], ca.w, cr); cr = fmaf(S4[c][4], cb.x, cr);
        cr = fmaf(S4[c][5], cb.y, cr); cr = fmaf(S4[c][6], cb.z, cr);
        cr = fmaf(S4[c][7], cb.w, cr); cr = fmaf(S4[c][8], cd.x, cr);
        cr = fmaf(S4[c][9], cd.y, cr);
        float tv = f1p[c] + f2q[j] - 2.f * cr;
        Kc[c][j] = __expf(-COST_SCALE * tv);
      }
    }

    // ---- Sinkhorn (v starts at ones) ----
    #pragma unroll
    for (int j = 0; j < NM; ++j) vv[j] = 1.f;
    for (int it = 0; it < SINK_IT; ++it) {
      #pragma unroll
      for (int c = 0; c < 4; ++c) {
        float d = Kc[c][0] * vv[0];
        #pragma unroll
        for (int j = 1; j < NM; ++j) d = fmaf(Kc[c][j], vv[j], d);
        uu[c] = pw * __builtin_amdgcn_rcpf(d);
      }
      #pragma unroll
      for (int j = 0; j < NM; ++j) {
        float w = Kc[0][j] * uu[0];
        w = fmaf(Kc[1][j], uu[1], w);
        w = fmaf(Kc[2][j], uu[2], w);
        w = fmaf(Kc[3][j], uu[3], w);
        float cs = allsum32(w);
        vv[j] = qv[j] * __builtin_amdgcn_rcpf(cs);
      }
    }

    // ---- P = diag(u) K diag(v) -> LDS ----
    __syncthreads();   // single-wave block: just drains LDS, ~free
    #pragma unroll
    for (int c = 0; c < 4; ++c) {
      float x[NM];
      #pragma unroll
      for (int j = 0; j < NM; ++j) x[j] = uu[c] * Kc[c][j] * vv[j];
      float* row = &Pls[p][sub + 32 * c][0];
      *(float4*)row       = make_float4(x[0], x[1], x[2], x[3]);
      *(float4*)(row + 4) = make_float4(x[4], x[5], x[6], x[7]);
      *(float2*)(row + 8) = make_float2(x[8], x[9]);
    }
    __syncthreads();
  }

  // ---- GW = sum_ij tens(P)_ij * P_ij ----
  float acc = 0.f;
  {
    float S4[4][NM];
    #pragma unroll
    for (int c = 0; c < 4; ++c) gatherRow(sub + 32 * c, S4[c]);
    #pragma unroll
    for (int j = 0; j < NM; ++j) {
      const float* c2r = &C2s[p][j][0];
      float4 ca = *(const float4*)c2r;
      float4 cb = *(const float4*)(c2r + 4);
      float2 cd = *(const float2*)(c2r + 8);
      #pragma unroll
      for (int c = 0; c < 4; ++c) {
        float cr = S4[c][0] * ca.x;
        cr = fmaf(S4[c][1], ca.y, cr); cr = fmaf(S4[c][2], ca.z, cr);
        cr = fmaf(S4[c][3], ca.w, cr); cr = fmaf(S4[c][4], cb.x, cr);
        cr = fmaf(S4[c][5], cb.y, cr); cr = fmaf(S4[c][6], cb.z, cr);
        cr = fmaf(S4[c][7], cb.w, cr); cr = fmaf(S4[c][8], cd.x, cr);
        cr = fmaf(S4[c][9], cd.y, cr);
        float tv = f1p[c] + f2q[j] - 2.f * cr;
        float Pv = uu[c] * Kc[c][j] * vv[j];
        acc = fmaf(tv, Pv, acc);
      }
    }
  }
  float total = allsum32(acc);
  if (sub == 0) out[b * NT + t0 + p] = total;
}

extern "C" void kernel_launch(void* const* d_in, const int* in_sizes, int n_in,
                              void* d_out, int out_size, void* d_ws, size_t ws_size,
                              hipStream_t stream) {
  // inputs: 0 x(f32, unused) 1 edge_index(int32) 2 batch(int32, unused)
  //         3 tplt_adjacencies(f32) 4 tplt_features(f32, unused) 5 q0(f32)
  const int* ei   = (const int*)d_in[1];
  const float* c2 = (const float*)d_in[3];
  const float* q0 = (const float*)d_in[5];
  float* out      = (float*)d_out;
  const int E  = in_sizes[1] / 2;
  const int ne = E / NGRAPH;
  tgw_kernel<<<dim3(NGRAPH * 8), dim3(64), 0, stream>>>(ei, c2, q0, out, E, ne);
}

// Round 5
// 200.470 us; speedup vs baseline: 1.1723x; 1.0164x over previous
//
#include <hip/hip_runtime.h>

#define NGRAPH 256
#define NN     128   // nodes per graph
#define NT     16    // templates
#define NM     10    // template nodes
#define OUTER_IT 5
#define SINK_IT  20

// K = exp(-20*tens) = exp2(-20*log2(e)*tens)
#define SC1  28.85390081777927f    // 20*log2(e)
#define SC2  57.70780163555854f    // 40*log2(e)

typedef unsigned long long u64;
typedef float v2f __attribute__((ext_vector_type(2)));
typedef float v4f __attribute__((ext_vector_type(4)));

static __device__ __forceinline__ v2f pkfma(v2f a, v2f b, v2f c) {
  return __builtin_elementwise_fma(a, b, c);
}
static __device__ __forceinline__ v2f bc2(float s) { return (v2f){s, s}; }

// DPP xor-butterfly add within a 16-lane row (masks {1,2,7,15} span (Z2)^4).
template <int CTRL>
__device__ __forceinline__ float dpp_add(float a) {
  int t = __builtin_amdgcn_update_dpp(0, __float_as_int(a), CTRL, 0xf, 0xf, true);
  return a + __int_as_float(t);
}
// Sum over each 32-lane group; result broadcast to all lanes of the group.
__device__ __forceinline__ float allsum32(float x) {
  x = dpp_add<0xB1>(x);    // quad_perm xor 1
  x = dpp_add<0x4E>(x);    // quad_perm xor 2
  x = dpp_add<0x141>(x);   // row_half_mirror: xor 7
  x = dpp_add<0x140>(x);   // row_mirror: xor 15
  int sw = __builtin_amdgcn_ds_swizzle(__float_as_int(x), 0x401F); // xor 16
  return x + __int_as_float(sw);
}

// 32 lanes per (graph b, template t) pair, 2 pairs per 64-thread single-wave
// block. Lane owns 4 rows r = sub + 32*c. Adjacency: LDS bitmask (shared).
// P: LDS fp32, row stride 12 floats. All fp32 math packed 2-wide over the
// 10-column axis (v_pk_fma_f32).
__global__ __launch_bounds__(64, 2)
void tgw_kernel(const int* __restrict__ ei,
                const float* __restrict__ tadj,
                const float* __restrict__ q0g,
                float* __restrict__ out,
                int E, int ne) {
  const int lane = threadIdx.x;
  const int p    = lane >> 5;        // pair slot 0/1
  const int sub  = lane & 31;
  const int b    = blockIdx.x >> 3;
  const int t0   = (blockIdx.x & 7) * 2;   // templates t0, t0+1

  __shared__ __align__(16) unsigned adj[NN][4];    // 2 KB
  __shared__ __align__(16) float Pls[2][NN][12];   // 12 KB
  __shared__ __align__(16) v2f C2T[2][NM][6];      // SC2*C2, [m][jpair], row 48B
  __shared__ float q0s[2][NM];

  // ---- stage ----
  for (int i = lane; i < NN * 4; i += 64) (&adj[0][0])[i] = 0u;
  // C2T[tt][m][jp] = SC2 * { C2[2jp][m], C2[2jp+1][m] }  (transposed pairs)
  for (int i = lane; i < 2 * NM * 5; i += 64) {
    int tt = i / 50, r = i % 50, m = r / 5, jp = r % 5;
    const float* bp = tadj + (t0 + tt) * NM * NM + m;
    C2T[tt][m][jp] = (v2f){bp[(2 * jp) * NM], bp[(2 * jp + 1) * NM]} * SC2;
  }
  if (lane < 2 * NM) q0s[lane / NM][lane % NM] = q0g[t0 * NM + lane];
  __syncthreads();

  // symmetric 0/1 adjacency from the edge list (dups/self-loops harmless)
  const int* srcp = ei;
  const int* dstp = ei + E;
  const int ebase = b * ne;
  for (int e = lane; e < ne; e += 64) {
    int s = srcp[ebase + e] & (NN - 1);
    int d = dstp[ebase + e] & (NN - 1);
    atomicOr(&adj[s][d >> 5], 1u << (d & 31));
    atomicOr(&adj[d][s >> 5], 1u << (s & 31));
  }
  __syncthreads();

  // ---- per-pair constants ----
  float qv[NM];
  {
    float mx = q0s[p][0];
    #pragma unroll
    for (int j = 1; j < NM; ++j) mx = fmaxf(mx, q0s[p][j]);
    float s = 0.f;
    #pragma unroll
    for (int j = 0; j < NM; ++j) { qv[j] = __expf(q0s[p][j] - mx); s += qv[j]; }
    float inv = __builtin_amdgcn_rcpf(s);
    #pragma unroll
    for (int j = 0; j < NM; ++j) qv[j] *= inv;
  }
  v2f q2[5];
  #pragma unroll
  for (int jp = 0; jp < 5; ++jp) q2[jp] = (v2f){qv[2 * jp], qv[2 * jp + 1]};

  // fq2[jp] = -SC1 * f2q[jpair]; f2q[j] = sum_m C2[j][m]^2 q[m]
  // C2 = C2T/SC2 => factor -SC1/SC2^2 = -1/(4*SC1)
  // qC2T[jp] = sum_m q[m] * C2T[m][jp]   (for the o==0 analytic cost)
  v2f fq2[5], qC2T[5];
  {
    #pragma unroll
    for (int jp = 0; jp < 5; ++jp) { fq2[jp] = (v2f){0.f, 0.f}; qC2T[jp] = (v2f){0.f, 0.f}; }
    #pragma unroll
    for (int m = 0; m < NM; ++m) {
      v2f qb = bc2(qv[m]);
      #pragma unroll
      for (int jp = 0; jp < 5; ++jp) {
        v2f c = C2T[p][m][jp];
        fq2[jp]  = pkfma(c * c, qb, fq2[jp]);
        qC2T[jp] = pkfma(c, qb, qC2T[jp]);
      }
    }
    const float f = -1.0f / (4.0f * SC1);
    #pragma unroll
    for (int jp = 0; jp < 5; ++jp) fq2[jp] *= f;
  }

  const float pw = 1.0f / 128.0f;
  float f1p[4], m1f1[4];
  #pragma unroll
  for (int c = 0; c < 4; ++c) {
    uint4 mm = *(const uint4*)&adj[sub + 32 * c][0];
    u64 m0 = mm.x | ((u64)mm.y << 32), m1 = mm.z | ((u64)mm.w << 32);
    f1p[c]  = (float)(__popcll(m0) + __popcll(m1)) * pw;   // C1*C1 == C1
    m1f1[c] = -SC1 * f1p[c];
  }

  const float* Pbase = &Pls[p][0][0];
  // sparse gather S = (C1 @ P)[row r], packed pairs over m
  auto gatherRow = [&](int r, v2f* S2) {
    uint4 mm = *(const uint4*)&adj[r][0];
    u64 m0 = mm.x | ((u64)mm.y << 32), m1 = mm.z | ((u64)mm.w << 32);
    #pragma unroll
    for (int h = 0; h < 5; ++h) S2[h] = (v2f){0.f, 0.f};
    while (m0) {
      int k = (int)__builtin_ctzll(m0); m0 &= m0 - 1;
      const float* row = Pbase + k * 12;
      v4f A = *(const v4f*)row;
      v4f B = *(const v4f*)(row + 4);
      v2f C = *(const v2f*)(row + 8);
      S2[0] += A.xy; S2[1] += A.zw; S2[2] += B.xy; S2[3] += B.zw; S2[4] += C;
    }
    while (m1) {
      int k = 64 + (int)__builtin_ctzll(m1); m1 &= m1 - 1;
      const float* row = Pbase + k * 12;
      v4f A = *(const v4f*)row;
      v4f B = *(const v4f*)(row + 4);
      v2f C = *(const v2f*)(row + 8);
      S2[0] += A.xy; S2[1] += A.zw; S2[2] += B.xy; S2[3] += B.zw; S2[4] += C;
    }
  };

  // arg2[c][jp] = -SC1*tens (packed over jpairs), from scalar S[m] per row
  auto costFromS = [&](float Sm[4][NM], v2f arg2[4][5]) {
    #pragma unroll
    for (int c = 0; c < 4; ++c) {
      v2f ib = fq2[0] + bc2(m1f1[c]);
      arg2[c][0] = ib;
      #pragma unroll
      for (int jp = 1; jp < 5; ++jp) arg2[c][jp] = fq2[jp] + bc2(m1f1[c]);
    }
    #pragma unroll
    for (int m = 0; m < NM; ++m) {
      v4f X = *(const v4f*)&C2T[p][m][0];   // jp 0,1
      v4f Y = *(const v4f*)&C2T[p][m][2];   // jp 2,3
      v2f Z = *(const v2f*)&C2T[p][m][4];   // jp 4
      #pragma unroll
      for (int c = 0; c < 4; ++c) {
        v2f sb = bc2(Sm[c][m]);
        arg2[c][0] = pkfma(sb, X.xy, arg2[c][0]);
        arg2[c][1] = pkfma(sb, X.zw, arg2[c][1]);
        arg2[c][2] = pkfma(sb, Y.xy, arg2[c][2]);
        arg2[c][3] = pkfma(sb, Y.zw, arg2[c][3]);
        arg2[c][4] = pkfma(sb, Z,    arg2[c][4]);
      }
    }
  };

  v2f K2[4][5], v2[5], arg2[4][5];
  float uu[4];

  for (int o = 0; o < OUTER_IT; ++o) {
    // ---- cost -> arg2 -> K = exp2(arg) ----
    if (o == 0) {
      // P0 = p q^T => S[c][m] = f1p[c]*q[m] => sum_m S C2T = f1p[c]*qC2T
      #pragma unroll
      for (int c = 0; c < 4; ++c) {
        v2f fb = bc2(f1p[c]);
        v2f ob = bc2(m1f1[c]);
        #pragma unroll
        for (int jp = 0; jp < 5; ++jp)
          arg2[c][jp] = pkfma(fb, qC2T[jp], fq2[jp] + ob);
      }
    } else {
      float Sm[4][NM];
      #pragma unroll
      for (int c = 0; c < 4; ++c) {
        v2f S2[5];
        gatherRow(sub + 32 * c, S2);
        #pragma unroll
        for (int h = 0; h < 5; ++h) { Sm[c][2 * h] = S2[h].x; Sm[c][2 * h + 1] = S2[h].y; }
      }
      costFromS(Sm, arg2);
    }
    #pragma unroll
    for (int c = 0; c < 4; ++c)
      #pragma unroll
      for (int jp = 0; jp < 5; ++jp)
        K2[c][jp] = (v2f){exp2f(arg2[c][jp].x), exp2f(arg2[c][jp].y)};

    // ---- Sinkhorn (v starts at ones) ----
    #pragma unroll
    for (int jp = 0; jp < 5; ++jp) v2[jp] = (v2f){1.f, 1.f};
    for (int it = 0; it < SINK_IT; ++it) {
      #pragma unroll
      for (int c = 0; c < 4; ++c) {
        v2f d2 = K2[c][0] * v2[0];
        d2 = pkfma(K2[c][1], v2[1], d2);
        d2 = pkfma(K2[c][2], v2[2], d2);
        d2 = pkfma(K2[c][3], v2[3], d2);
        d2 = pkfma(K2[c][4], v2[4], d2);
        uu[c] = pw * __builtin_amdgcn_rcpf(d2.x + d2.y);
      }
      #pragma unroll
      for (int jp = 0; jp < 5; ++jp) {
        v2f w2 = K2[0][jp] * bc2(uu[0]);
        w2 = pkfma(K2[1][jp], bc2(uu[1]), w2);
        w2 = pkfma(K2[2][jp], bc2(uu[2]), w2);
        w2 = pkfma(K2[3][jp], bc2(uu[3]), w2);
        float cx = allsum32(w2.x);
        float cy = allsum32(w2.y);
        v2[jp] = (v2f){q2[jp].x * __builtin_amdgcn_rcpf(cx),
                       q2[jp].y * __builtin_amdgcn_rcpf(cy)};
      }
    }

    // ---- P = diag(u) K diag(v) -> LDS ----
    __syncthreads();   // single-wave block: just drains LDS ops, ~free
    #pragma unroll
    for (int c = 0; c < 4; ++c) {
      v2f ub = bc2(uu[c]);
      v2f x0 = K2[c][0] * ub * v2[0];
      v2f x1 = K2[c][1] * ub * v2[1];
      v2f x2 = K2[c][2] * ub * v2[2];
      v2f x3 = K2[c][3] * ub * v2[3];
      v2f x4 = K2[c][4] * ub * v2[4];
      float* row = &Pls[p][sub + 32 * c][0];
      *(v4f*)row       = (v4f){x0.x, x0.y, x1.x, x1.y};
      *(v4f*)(row + 4) = (v4f){x2.x, x2.y, x3.x, x3.y};
      *(v2f*)(row + 8) = x4;
    }
    __syncthreads();
  }

  // ---- GW = sum_ij tens(P)_ij * P_ij,  tens = arg * (-1/SC1) ----
  float acc = 0.f;
  {
    float Sm[4][NM];
    #pragma unroll
    for (int c = 0; c < 4; ++c) {
      v2f S2[5];
      gatherRow(sub + 32 * c, S2);
      #pragma unroll
      for (int h = 0; h < 5; ++h) { Sm[c][2 * h] = S2[h].x; Sm[c][2 * h + 1] = S2[h].y; }
    }
    costFromS(Sm, arg2);
    const v2f nf = bc2(-1.0f / SC1);
    v2f acc2 = (v2f){0.f, 0.f};
    #pragma unroll
    for (int c = 0; c < 4; ++c) {
      v2f ub = bc2(uu[c]);
      #pragma unroll
      for (int jp = 0; jp < 5; ++jp) {
        v2f Pv = K2[c][jp] * ub * v2[jp];
        acc2 = pkfma(arg2[c][jp] * nf, Pv, acc2);
      }
    }
    acc = acc2.x + acc2.y;
  }
  float total = allsum32(acc);
  if (sub == 0) out[b * NT + t0 + p] = total;
}

extern "C" void kernel_launch(void* const* d_in, const int* in_sizes, int n_in,
                              void* d_out, int out_size, void* d_ws, size_t ws_size,
                              hipStream_t stream) {
  // inputs: 0 x(f32, unused) 1 edge_index(int32) 2 batch(int32, unused)
  //         3 tplt_adjacencies(f32) 4 tplt_features(f32, unused) 5 q0(f32)
  const int* ei   = (const int*)d_in[1];
  const float* c2 = (const float*)d_in[3];
  const float* q0 = (const float*)d_in[5];
  float* out      = (float*)d_out;
  const int E  = in_sizes[1] / 2;
  const int ne = E / NGRAPH;
  tgw_kernel<<<dim3(NGRAPH * 8), dim3(64), 0, stream>>>(ei, c2, q0, out, E, ne);
}